// Round 12
// baseline (365.111 us; speedup 1.0000x reference)
//
#include <hip/hip_runtime.h>
#include <math.h>

#define N_B 64
#define T_LEN 2048
#define D_DIM 512
#define NEG (-1e9f)
#define G_BLK 2048              // proven best (R7)
#define MIN_W 16                // floor on rows/block (bounds J_MAX)
#define J_MAX 132               // >= T_LEN/MIN_W + 2 partial slots per batch

// ws layout: done[N_B] ints (zeroed each launch via hipMemsetAsync), pad to
// 1KB, then floats m_ws[N*J_MAX], l_ws[N*J_MAX], o_ws[N*J_MAX*D].

__device__ __forceinline__ float dot8(const float4& qa, const float4& qb,
                                      const float4& ka, const float4& kb) {
    return qa.x * ka.x + qa.y * ka.y + qa.z * ka.z + qa.w * ka.w
         + qb.x * kb.x + qb.y * kb.y + qb.z * kb.z + qb.w * kb.w;
}

// rows(n) = len_n == 0 ? T : len_n  (len==0 does uniform V-mean over all T)
__device__ __forceinline__ int useful_rows(int len) {
    return (len == 0) ? T_LEN : len;
}

// ---------------------------------------------------------------------------
// Fused: block b owns global rows [b*W, (b+1)*W) (exact balance). Per batch
// segment: online softmax in registers, LDS merge, write partial slot
// j = b - floor(s_n/W), then done[n]++. The LAST finisher for batch n runs
// the LSE-combine for n inline (split-K idiom, device-scope atomics).
// ---------------------------------------------------------------------------
__global__ __launch_bounds__(256) void attn_fused(
    const float* __restrict__ q,     // (N, D)
    const float* __restrict__ key,   // (T, N, D)
    const float* __restrict__ val,   // (T, N, D)
    const int*   __restrict__ lens,  // (N)
    int*   __restrict__ done,        // (N) zeroed before launch
    float* __restrict__ m_ws,        // (N, J_MAX)
    float* __restrict__ l_ws,        // (N, J_MAX)
    float* __restrict__ o_ws,        // (N, J_MAX, D)
    float* __restrict__ out)         // (N, D)
{
    const int tid  = threadIdx.x;
    const int wave = tid >> 6;
    const int lane = tid & 63;
    const int d0   = 2 * tid;
    const size_t rstride = (size_t)N_B * D_DIM;   // t-stride in floats

    __shared__ int   pre_sm[N_B + 1];
    __shared__ float acc_sm[4][D_DIM];
    __shared__ float ml_sm[4][2];
    __shared__ float s_sm[J_MAX];
    __shared__ float S_sm;
    __shared__ int   flag_sm;

    // Wave 0 computes the rows-prefix from lens.
    if (wave == 0) {
        int incl = useful_rows(lens[lane]);
        #pragma unroll
        for (int off = 1; off < 64; off <<= 1) {
            const int y = __shfl_up(incl, off);
            if (lane >= off) incl += y;
        }
        if (lane == 0) pre_sm[0] = 0;
        pre_sm[1 + lane] = incl;
    }
    __syncthreads();

    const int total = pre_sm[N_B];
    int W = (total + G_BLK - 1) / G_BLK;
    if (W < MIN_W) W = MIN_W;
    const int r0 = blockIdx.x * W;
    if (r0 >= total) return;
    const int r1 = min(r0 + W, total);

    // binary search: largest n with s_n <= r0
    int lo = 0, hi = N_B;
    while (hi - lo > 1) {
        const int mid = (lo + hi) >> 1;
        if (pre_sm[mid] <= r0) lo = mid; else hi = mid;
    }
    int n = lo;
    int r = r0;

    while (r < r1) {
        const int sn    = pre_sm[n];
        const int sn1   = pre_sm[n + 1];
        const int ta    = r - sn;                  // local rows [ta, tb)
        const int tb    = min(r1, sn1) - sn;
        const int j     = blockIdx.x - (sn / W);   // deterministic slot
        const int len_n = lens[n];

        float acc[8];
        #pragma unroll
        for (int jj = 0; jj < 8; ++jj) acc[jj] = 0.0f;
        float m = -INFINITY, l = 0.0f;

        if (len_n == 0) {
            // all energies NEG -> uniform weights: sum V, l = row count.
            int cnt = 0;
            const float* vr = val + ((size_t)(ta + wave) * N_B + n) * D_DIM
                            + 8 * lane;
            for (int t = ta + wave; t < tb; t += 4) {
                const float4 va = *reinterpret_cast<const float4*>(vr);
                const float4 vb = *reinterpret_cast<const float4*>(vr + 4);
                vr += 4 * rstride;
                acc[0] += va.x; acc[1] += va.y; acc[2] += va.z; acc[3] += va.w;
                acc[4] += vb.x; acc[5] += vb.y; acc[6] += vb.z; acc[7] += vb.w;
                ++cnt;
            }
            m = NEG;
            l = (float)cnt;
        } else {
            // every row in [ta, tb) is unmasked by construction.
            int t = ta + wave;
            if (t < tb) {
                const float4* q4 = reinterpret_cast<const float4*>(
                    q + (size_t)n * D_DIM) + 2 * lane;
                const float4 qa = q4[0];
                const float4 qb = q4[1];

                const float* kr = key + ((size_t)t * N_B + n) * D_DIM + 8 * lane;
                const float* vr = val + ((size_t)t * N_B + n) * D_DIM + 8 * lane;

                float4 ka = *reinterpret_cast<const float4*>(kr);
                float4 kb = *reinterpret_cast<const float4*>(kr + 4);
                float4 na = ka, nb = kb;

                for (; t < tb; t += 4) {
                    const float4 va = *reinterpret_cast<const float4*>(vr);
                    const float4 vb = *reinterpret_cast<const float4*>(vr + 4);
                    vr += 4 * rstride;
                    if (t + 4 < tb) {
                        na = *reinterpret_cast<const float4*>(kr + 4 * rstride);
                        nb = *reinterpret_cast<const float4*>(kr + 4 * rstride + 4);
                    }
                    kr += 4 * rstride;

                    float e = dot8(qa, qb, ka, kb);
                    #pragma unroll
                    for (int off = 32; off; off >>= 1) e += __shfl_xor(e, off);

                    if (e > m) {                        // wave-uniform
                        const float sc = __expf(m - e); // first iter: 0
                        l *= sc;
                        #pragma unroll
                        for (int jj = 0; jj < 8; ++jj) acc[jj] *= sc;
                        m = e;
                    }
                    const float p = __expf(e - m);
                    l += p;
                    acc[0] += p * va.x; acc[1] += p * va.y;
                    acc[2] += p * va.z; acc[3] += p * va.w;
                    acc[4] += p * vb.x; acc[5] += p * vb.y;
                    acc[6] += p * vb.z; acc[7] += p * vb.w;

                    ka = na; kb = nb;
                }
            }
            // wave with no rows keeps (-inf, 0, 0) -> zero at merge.
        }

        // ---- merge 4 waves, write partial slot (n, j) ----
        *reinterpret_cast<float4*>(&acc_sm[wave][8 * lane]) =
            make_float4(acc[0], acc[1], acc[2], acc[3]);
        *reinterpret_cast<float4*>(&acc_sm[wave][8 * lane + 4]) =
            make_float4(acc[4], acc[5], acc[6], acc[7]);
        if (lane == 0) { ml_sm[wave][0] = m; ml_sm[wave][1] = l; }
        __syncthreads();

        const float m0 = ml_sm[0][0], m1 = ml_sm[1][0];
        const float m2 = ml_sm[2][0], m3 = ml_sm[3][0];
        const float M  = fmaxf(fmaxf(m0, m1), fmaxf(m2, m3));  // finite
        const float s0 = __expf(m0 - M), s1 = __expf(m1 - M);
        const float s2 = __expf(m2 - M), s3 = __expf(m3 - M);

        float2 rr;
        rr.x = s0 * acc_sm[0][d0]     + s1 * acc_sm[1][d0]
             + s2 * acc_sm[2][d0]     + s3 * acc_sm[3][d0];
        rr.y = s0 * acc_sm[0][d0 + 1] + s1 * acc_sm[1][d0 + 1]
             + s2 * acc_sm[2][d0 + 1] + s3 * acc_sm[3][d0 + 1];
        *reinterpret_cast<float2*>(
            o_ws + ((size_t)n * J_MAX + j) * D_DIM + d0) = rr;

        if (tid == 0) {
            m_ws[n * J_MAX + j] = M;
            l_ws[n * J_MAX + j] = s0 * ml_sm[0][1] + s1 * ml_sm[1][1]
                                + s2 * ml_sm[2][1] + s3 * ml_sm[3][1];
        }

        // ---- completion count; last finisher combines batch n ----
        __threadfence();                 // publish slot writes (device scope)
        __syncthreads();                 // all threads' stores issued
        const int b0 = sn / W;
        const int b1 = (sn1 - 1) / W;
        const int J  = b1 - b0 + 1;
        if (tid == 0) flag_sm = atomicAdd(&done[n], 1);
        __syncthreads();

        if (flag_sm == J - 1) {
            __threadfence();             // acquire other blocks' slot writes

            if (wave == 0) {             // compute per-slot scales
                float mj[3], lj[3];
                float Mx = -INFINITY;
                #pragma unroll
                for (int k = 0; k < 3; ++k) {
                    const int jdx = lane + 64 * k;
                    const bool ok = (jdx < J);
                    mj[k] = ok ? m_ws[n * J_MAX + jdx] : -INFINITY;
                    lj[k] = ok ? l_ws[n * J_MAX + jdx] : 0.0f;
                    Mx = fmaxf(Mx, mj[k]);
                }
                #pragma unroll
                for (int off = 32; off; off >>= 1)
                    Mx = fmaxf(Mx, __shfl_xor(Mx, off));
                float S = 0.0f;
                #pragma unroll
                for (int k = 0; k < 3; ++k) {
                    const int jdx = lane + 64 * k;
                    const float s = __expf(mj[k] - Mx);   // -inf -> 0
                    if (jdx < J) s_sm[jdx] = s;
                    S += s * lj[k];
                }
                #pragma unroll
                for (int off = 32; off; off >>= 1) S += __shfl_xor(S, off);
                if (lane == 0) S_sm = S;
            }
            __syncthreads();

            const float inv = 1.0f / S_sm;
            const float* op = o_ws + (size_t)n * J_MAX * D_DIM + d0;
            float2 a0 = {0, 0}, a1 = {0, 0}, a2 = {0, 0}, a3 = {0, 0};
            int jj = 0;
            for (; jj + 3 < J; jj += 4) {
                const float2 v0 = *reinterpret_cast<const float2*>(
                    op + (size_t)jj * D_DIM);
                const float2 v1 = *reinterpret_cast<const float2*>(
                    op + (size_t)(jj + 1) * D_DIM);
                const float2 v2 = *reinterpret_cast<const float2*>(
                    op + (size_t)(jj + 2) * D_DIM);
                const float2 v3 = *reinterpret_cast<const float2*>(
                    op + (size_t)(jj + 3) * D_DIM);
                a0.x += s_sm[jj]     * v0.x; a0.y += s_sm[jj]     * v0.y;
                a1.x += s_sm[jj + 1] * v1.x; a1.y += s_sm[jj + 1] * v1.y;
                a2.x += s_sm[jj + 2] * v2.x; a2.y += s_sm[jj + 2] * v2.y;
                a3.x += s_sm[jj + 3] * v3.x; a3.y += s_sm[jj + 3] * v3.y;
            }
            for (; jj < J; ++jj) {
                const float2 v0 = *reinterpret_cast<const float2*>(
                    op + (size_t)jj * D_DIM);
                a0.x += s_sm[jj] * v0.x; a0.y += s_sm[jj] * v0.y;
            }
            float2 res;
            res.x = ((a0.x + a1.x) + (a2.x + a3.x)) * inv;
            res.y = ((a0.y + a1.y) + (a2.y + a3.y)) * inv;
            *reinterpret_cast<float2*>(out + (size_t)n * D_DIM + d0) = res;
        }

        r = min(r1, sn1);
        ++n;
        if (r < r1) __syncthreads();   // LDS reuse before next segment
    }
}

extern "C" void kernel_launch(void* const* d_in, const int* in_sizes, int n_in,
                              void* d_out, int out_size, void* d_ws, size_t ws_size,
                              hipStream_t stream) {
    const float* q    = (const float*)d_in[0];
    const float* key  = (const float*)d_in[1];
    const float* val  = (const float*)d_in[2];
    const int*   lens = (const int*)d_in[3];
    float*       out  = (float*)d_out;

    int*   done = (int*)d_ws;
    float* m_ws = (float*)((char*)d_ws + 1024);
    float* l_ws = m_ws + N_B * J_MAX;
    float* o_ws = l_ws + N_B * J_MAX;     // 64*132*512*4B ~= 17.3 MB

    hipMemsetAsync(done, 0, N_B * sizeof(int), stream);
    attn_fused<<<G_BLK, 256, 0, stream>>>(q, key, val, lens, done,
                                          m_ws, l_ws, o_ws, out);
}

// Round 13
// 54.845 us; speedup vs baseline: 6.6571x; 6.6571x over previous
//
#include <hip/hip_runtime.h>
#include <math.h>

#define N_B 64
#define T_LEN 2048
#define D_DIM 512
#define NEG (-1e9f)
#define G_BLK 2048              // proven best (R7: 54.2 us)
#define MIN_W 16                // floor on rows/block (bounds J_MAX)
#define J_MAX 132               // >= T_LEN/MIN_W + 2 partial slots per batch

// ws floats: m_ws[N*J_MAX], l_ws[N*J_MAX], o_ws[N*J_MAX*D]. No ctl/setup —
// every block recomputes the 64-entry rows-prefix from lens (L2-resident).
// NOTE (R11/R12 lesson): do NOT fuse the combine into the streaming kernel —
// the epilogue perturbs regalloc and spills the hot loop (84->48/52 VGPR,
// 6x slowdown, counter-evidenced). Two kernels is the protective structure.

__device__ __forceinline__ float dot8(const float4& qa, const float4& qb,
                                      const float4& ka, const float4& kb) {
    return qa.x * ka.x + qa.y * ka.y + qa.z * ka.z + qa.w * ka.w
         + qb.x * kb.x + qb.y * kb.y + qb.z * kb.z + qb.w * kb.w;
}

// rows(n) = len_n == 0 ? T : len_n  (len==0 does uniform V-mean over all T)
__device__ __forceinline__ int useful_rows(int len) {
    return (len == 0) ? T_LEN : len;
}

// ---------------------------------------------------------------------------
// Partial: block b owns global rows [b*W, (b+1)*W) of the flattened row list —
// exact per-block balance. Per batch-segment: 4 waves (strided by 4 rows) run
// the online-softmax loop in registers, merge via LDS, write partial slot
// j = b - floor(s_n / W).
// ---------------------------------------------------------------------------
__global__ __launch_bounds__(256) void attn_partial(
    const float* __restrict__ q,     // (N, D)
    const float* __restrict__ key,   // (T, N, D)
    const float* __restrict__ val,   // (T, N, D)
    const int*   __restrict__ lens,  // (N)
    float* __restrict__ m_ws,        // (N, J_MAX)
    float* __restrict__ l_ws,        // (N, J_MAX)
    float* __restrict__ o_ws)        // (N, J_MAX, D)
{
    const int tid  = threadIdx.x;
    const int wave = tid >> 6;
    const int lane = tid & 63;
    const int d0   = 2 * tid;
    const size_t rstride = (size_t)N_B * D_DIM;   // t-stride in floats

    __shared__ int   pre_sm[N_B + 1];
    __shared__ float acc_sm[4][D_DIM];
    __shared__ float ml_sm[4][2];

    // Wave 0 computes the rows-prefix from lens (no setup kernel).
    if (wave == 0) {
        int incl = useful_rows(lens[lane]);
        #pragma unroll
        for (int off = 1; off < 64; off <<= 1) {
            const int y = __shfl_up(incl, off);
            if (lane >= off) incl += y;
        }
        if (lane == 0) pre_sm[0] = 0;
        pre_sm[1 + lane] = incl;
    }
    __syncthreads();

    const int total = pre_sm[N_B];
    int W = (total + G_BLK - 1) / G_BLK;
    if (W < MIN_W) W = MIN_W;
    const int r0 = blockIdx.x * W;
    if (r0 >= total) return;
    const int r1 = min(r0 + W, total);

    // binary search: largest n with s_n <= r0
    int lo = 0, hi = N_B;
    while (hi - lo > 1) {
        const int mid = (lo + hi) >> 1;
        if (pre_sm[mid] <= r0) lo = mid; else hi = mid;
    }
    int n = lo;
    int r = r0;

    while (r < r1) {
        const int sn    = pre_sm[n];
        const int sn1   = pre_sm[n + 1];
        const int ta    = r - sn;                  // local row range [ta, tb)
        const int tb    = min(r1, sn1) - sn;
        const int j     = blockIdx.x - (sn / W);   // deterministic slot
        const int len_n = lens[n];

        float acc[8];
        #pragma unroll
        for (int jj = 0; jj < 8; ++jj) acc[jj] = 0.0f;
        float m = -INFINITY, l = 0.0f;

        if (len_n == 0) {
            // all energies NEG -> uniform weights: sum V, l = row count.
            int cnt = 0;
            const float* vr = val + ((size_t)(ta + wave) * N_B + n) * D_DIM
                            + 8 * lane;
            for (int t = ta + wave; t < tb; t += 4) {
                const float4 va = *reinterpret_cast<const float4*>(vr);
                const float4 vb = *reinterpret_cast<const float4*>(vr + 4);
                vr += 4 * rstride;
                acc[0] += va.x; acc[1] += va.y; acc[2] += va.z; acc[3] += va.w;
                acc[4] += vb.x; acc[5] += vb.y; acc[6] += vb.z; acc[7] += vb.w;
                ++cnt;
            }
            m = NEG;
            l = (float)cnt;
        } else {
            // every row in [ta, tb) is unmasked by construction.
            int t = ta + wave;
            if (t < tb) {
                const float4* q4 = reinterpret_cast<const float4*>(
                    q + (size_t)n * D_DIM) + 2 * lane;
                const float4 qa = q4[0];
                const float4 qb = q4[1];

                const float* kr = key + ((size_t)t * N_B + n) * D_DIM + 8 * lane;
                const float* vr = val + ((size_t)t * N_B + n) * D_DIM + 8 * lane;

                float4 ka = *reinterpret_cast<const float4*>(kr);
                float4 kb = *reinterpret_cast<const float4*>(kr + 4);
                float4 na = ka, nb = kb;

                for (; t < tb; t += 4) {
                    const float4 va = *reinterpret_cast<const float4*>(vr);
                    const float4 vb = *reinterpret_cast<const float4*>(vr + 4);
                    vr += 4 * rstride;
                    if (t + 4 < tb) {
                        na = *reinterpret_cast<const float4*>(kr + 4 * rstride);
                        nb = *reinterpret_cast<const float4*>(kr + 4 * rstride + 4);
                    }
                    kr += 4 * rstride;

                    float e = dot8(qa, qb, ka, kb);
                    #pragma unroll
                    for (int off = 32; off; off >>= 1) e += __shfl_xor(e, off);

                    if (e > m) {                        // wave-uniform
                        const float sc = __expf(m - e); // first iter: 0
                        l *= sc;
                        #pragma unroll
                        for (int jj = 0; jj < 8; ++jj) acc[jj] *= sc;
                        m = e;
                    }
                    const float p = __expf(e - m);
                    l += p;
                    acc[0] += p * va.x; acc[1] += p * va.y;
                    acc[2] += p * va.z; acc[3] += p * va.w;
                    acc[4] += p * vb.x; acc[5] += p * vb.y;
                    acc[6] += p * vb.z; acc[7] += p * vb.w;

                    ka = na; kb = nb;
                }
            }
            // wave with no rows keeps (-inf, 0, 0) -> zero weight at merge.
        }

        // ---- merge 4 waves, write partial slot (n, j) ----
        *reinterpret_cast<float4*>(&acc_sm[wave][8 * lane]) =
            make_float4(acc[0], acc[1], acc[2], acc[3]);
        *reinterpret_cast<float4*>(&acc_sm[wave][8 * lane + 4]) =
            make_float4(acc[4], acc[5], acc[6], acc[7]);
        if (lane == 0) { ml_sm[wave][0] = m; ml_sm[wave][1] = l; }
        __syncthreads();

        const float m0 = ml_sm[0][0], m1 = ml_sm[1][0];
        const float m2 = ml_sm[2][0], m3 = ml_sm[3][0];
        const float M  = fmaxf(fmaxf(m0, m1), fmaxf(m2, m3));  // finite
        const float s0 = __expf(m0 - M), s1 = __expf(m1 - M);
        const float s2 = __expf(m2 - M), s3 = __expf(m3 - M);

        float2 rr;
        rr.x = s0 * acc_sm[0][d0]     + s1 * acc_sm[1][d0]
             + s2 * acc_sm[2][d0]     + s3 * acc_sm[3][d0];
        rr.y = s0 * acc_sm[0][d0 + 1] + s1 * acc_sm[1][d0 + 1]
             + s2 * acc_sm[2][d0 + 1] + s3 * acc_sm[3][d0 + 1];
        *reinterpret_cast<float2*>(
            o_ws + ((size_t)n * J_MAX + j) * D_DIM + d0) = rr;

        if (tid == 0) {
            m_ws[n * J_MAX + j] = M;
            l_ws[n * J_MAX + j] = s0 * ml_sm[0][1] + s1 * ml_sm[1][1]
                                + s2 * ml_sm[2][1] + s3 * ml_sm[3][1];
        }

        r = min(r1, sn1);
        ++n;
        if (r < r1) __syncthreads();   // acc_sm reuse only if another segment
    }
}

// ---------------------------------------------------------------------------
// Combine: per batch n, LSE-merge its J_n partial slots. Grid (N, 2):
// block (n, h) handles d = h*256 + tid. Slot loop 4-way unrolled for MLP.
// ---------------------------------------------------------------------------
__global__ __launch_bounds__(256) void attn_combine(
    const int*   __restrict__ lens,
    const float* __restrict__ m_ws,
    const float* __restrict__ l_ws,
    const float* __restrict__ o_ws,
    float* __restrict__ out)
{
    const int n   = blockIdx.x;
    const int tid = threadIdx.x;

    __shared__ float s_sm[J_MAX];
    __shared__ float S_sm;
    __shared__ int   J_sm;

    if (tid < 64) {
        // Recompute prefix from lens (one wave).
        int incl = useful_rows(lens[tid]);
        #pragma unroll
        for (int off = 1; off < 64; off <<= 1) {
            const int y = __shfl_up(incl, off);
            if (tid >= off) incl += y;
        }
        const int total = __shfl(incl, 63);
        int W = (total + G_BLK - 1) / G_BLK;
        if (W < MIN_W) W = MIN_W;
        const int sn1 = __shfl(incl, n);            // s_{n+1}
        const int sn  = (n == 0) ? 0 : __shfl(incl, n - 1);
        const int b0  = sn / W;
        const int b1  = (sn1 - 1) / W;
        const int J   = b1 - b0 + 1;                // <= J_MAX
        if (tid == 0) J_sm = J;

        float mj[3], lj[3];
        float M = -INFINITY;
        #pragma unroll
        for (int k = 0; k < 3; ++k) {
            const int jdx = tid + 64 * k;
            const bool ok = (jdx < J);
            mj[k] = ok ? m_ws[n * J_MAX + jdx] : -INFINITY;
            lj[k] = ok ? l_ws[n * J_MAX + jdx] : 0.0f;
            M = fmaxf(M, mj[k]);
        }
        #pragma unroll
        for (int off = 32; off; off >>= 1) M = fmaxf(M, __shfl_xor(M, off));
        float S = 0.0f;
        #pragma unroll
        for (int k = 0; k < 3; ++k) {
            const int jdx = tid + 64 * k;
            const float s = __expf(mj[k] - M);   // -inf -> 0
            if (jdx < J) s_sm[jdx] = s;
            S += s * lj[k];
        }
        #pragma unroll
        for (int off = 32; off; off >>= 1) S += __shfl_xor(S, off);
        if (tid == 0) S_sm = S;
    }
    __syncthreads();

    const int J = J_sm;
    const float inv = 1.0f / S_sm;
    const int d = blockIdx.y * 256 + tid;
    float acc0 = 0.0f, acc1 = 0.0f, acc2 = 0.0f, acc3 = 0.0f;
    const float* op = o_ws + (size_t)n * J_MAX * D_DIM + d;
    int jj = 0;
    for (; jj + 3 < J; jj += 4) {
        acc0 += s_sm[jj]     * op[(size_t)jj * D_DIM];
        acc1 += s_sm[jj + 1] * op[(size_t)(jj + 1) * D_DIM];
        acc2 += s_sm[jj + 2] * op[(size_t)(jj + 2) * D_DIM];
        acc3 += s_sm[jj + 3] * op[(size_t)(jj + 3) * D_DIM];
    }
    for (; jj < J; ++jj)
        acc0 += s_sm[jj] * op[(size_t)jj * D_DIM];

    out[(size_t)n * D_DIM + d] = ((acc0 + acc1) + (acc2 + acc3)) * inv;
}

extern "C" void kernel_launch(void* const* d_in, const int* in_sizes, int n_in,
                              void* d_out, int out_size, void* d_ws, size_t ws_size,
                              hipStream_t stream) {
    const float* q    = (const float*)d_in[0];
    const float* key  = (const float*)d_in[1];
    const float* val  = (const float*)d_in[2];
    const int*   lens = (const int*)d_in[3];
    float*       out  = (float*)d_out;

    float* m_ws = (float*)d_ws;
    float* l_ws = m_ws + N_B * J_MAX;
    float* o_ws = l_ws + N_B * J_MAX;     // 64*132*512*4B ~= 17.3 MB

    attn_partial<<<G_BLK, 256, 0, stream>>>(q, key, val, lens,
                                            m_ws, l_ws, o_ws);
    attn_combine<<<dim3(N_B, D_DIM / 256), 256, 0, stream>>>(lens, m_ws, l_ws,
                                                             o_ws, out);
}